// Round 16
// baseline (109.487 us; speedup 1.0000x reference)
//
#include <hip/hip_runtime.h>
#include <hip/hip_fp16.h>
#include <math.h>

#define NG 1000
#define NPN 512        // nodes per partition
#define PSH 9          // log2(NPN)
#define MAXPART 256    // >= ceil(N/NPN); N=100K -> 196
#define K1BLK 256      // blocks for edge-chunk kernels
#define CAP 9216       // per-partition ibuf capacity (mean 8163 + 11.7 sigma)

// ---- K0: zero [pooled | cnt | gcnt] ----
__global__ void init_kernel(int4* __restrict__ p, int n4) {
    int i = blockIdx.x * blockDim.x + threadIdx.x;
    if (i < n4) p[i] = make_int4(0, 0, 0, 0);
}

// ---- K1: scatter edges into CAP-strided partition regions (block-reserved runs) ----
__global__ void __launch_bounds__(256) scatter_kernel(const int* __restrict__ src,
                                                      const int* __restrict__ dst,
                                                      int* __restrict__ gcnt,
                                                      int* __restrict__ ibuf,
                                                      int E, int CH, int NPART) {
    __shared__ int h[MAXPART];
    __shared__ int gb[MAXPART];
    int b = blockIdx.x, t = threadIdx.x;
    h[t] = 0;
    __syncthreads();
    int beg = b * CH, end = min(E, beg + CH);
    for (int e = beg + t; e < end; e += 256) atomicAdd(&h[dst[e] >> PSH], 1);
    __syncthreads();
    if (t < NPART) gb[t] = t * CAP + (h[t] > 0 ? atomicAdd(&gcnt[t], h[t]) : 0);
    __syncthreads();
    h[t] = 0;   // reuse as local cursor
    __syncthreads();
    for (int e = beg + t; e < end; e += 256) {
        int s = src[e], d = dst[e];
        int p = d >> PSH;
        int pos = gb[p] + atomicAdd(&h[p], 1);
        ibuf[pos] = ((d & (NPN - 1)) << 17) | s;   // N < 2^17
    }
}

// ---- K2: per-partition node CSR (strided ibuf -> packed csr) + rowptr + fused xform ----
__global__ void __launch_bounds__(256) part_kernel(const int* __restrict__ gcnt,
                                                   const int* __restrict__ ibuf,
                                                   int* __restrict__ csr,
                                                   int* __restrict__ rowptr,
                                                   const float* __restrict__ X,
                                                   const float* __restrict__ W1,
                                                   __half* __restrict__ A1h,
                                                   int N, int E, int NPART) {
    __shared__ int h[NPN];
    __shared__ int ex[NPN];
    __shared__ int cur[NPN];
    __shared__ int sm[256];
    __shared__ float sW1[512];
    __shared__ int sWbeg;
    int p = blockIdx.x, t = threadIdx.x;
    int base = p * NPN;
    for (int k = t; k < NPN; k += 256) h[k] = 0;
    sW1[t] = W1[t];
    sW1[t + 256] = W1[t + 256];
    if (t < 64) {   // inline exclusive scan of gcnt -> this partition's packed csr base
        int lane = t;
        int v[4];
        int s = 0;
#pragma unroll
        for (int k = 0; k < 4; k++) {
            int idx = lane * 4 + k;
            v[k] = (idx < NPART) ? gcnt[idx] : 0;
            s += v[k];
        }
        int incl = s;
        for (int off = 1; off < 64; off <<= 1) {
            int u = __shfl_up(incl, off);
            if (lane >= off) incl += u;
        }
        int run = incl - s;
#pragma unroll
        for (int k = 0; k < 4; k++) {
            int idx = lane * 4 + k;
            if (idx == p) sWbeg = run;
            run += v[k];
        }
    }
    if (p == 0 && t == 0) rowptr[N] = E;
    __syncthreads();
    int count = gcnt[p];
    int rbeg = p * CAP;     // strided read base
    int wbeg = sWbeg;       // packed write base
    for (int e = t; e < count; e += 256) atomicAdd(&h[ibuf[rbeg + e] >> 17], 1);
    __syncthreads();
    int a0 = h[2 * t], a1 = h[2 * t + 1];
    int s = a0 + a1;
    sm[t] = s;
    __syncthreads();
    for (int o = 1; o < 256; o <<= 1) {
        int u = (t >= o) ? sm[t - o] : 0;
        __syncthreads();
        sm[t] += u;
        __syncthreads();
    }
    int exc = sm[t] - s;
    ex[2 * t] = exc;          cur[2 * t] = exc;
    ex[2 * t + 1] = exc + a0; cur[2 * t + 1] = exc + a0;
    __syncthreads();
    for (int k = t; k < NPN; k += 256) {
        int n = base + k;
        if (n < N) rowptr[n] = wbeg + ex[k];
    }
    for (int e = t; e < count; e += 256) {
        int w = ibuf[rbeg + e];
        int ln = w >> 17;
        int pos = wbeg + atomicAdd(&cur[ln], 1);
        csr[pos] = w & 0x1FFFF;
    }
    // fused xform: A1h[n] = (x[n] @ W1^T) * rsqrt(deg+1)
    for (int k = t; k < NPN; k += 256) {
        int n = base + k;
        if (n >= N) continue;
        float dd = rsqrtf((float)h[k] + 1.0f);
        float xv[32];
        const float4* xp = (const float4*)(X + (size_t)n * 32);
#pragma unroll
        for (int qq = 0; qq < 8; qq++) {
            float4 v = xp[qq];
            xv[4*qq+0] = v.x; xv[4*qq+1] = v.y; xv[4*qq+2] = v.z; xv[4*qq+3] = v.w;
        }
        union { __half2 h2[8]; uint4 u4[2]; } pk;
#pragma unroll
        for (int j2 = 0; j2 < 8; j2++) {
            float o[2];
#pragma unroll
            for (int jj = 0; jj < 2; jj++) {
                int j = j2 * 2 + jj;
                float a = 0.f;
#pragma unroll
                for (int kk = 0; kk < 32; kk++) a += xv[kk] * sW1[j * 32 + kk];
                o[jj] = a * dd;
            }
            pk.h2[j2] = __floats2half2_rn(o[0], o[1]);
        }
        uint4* yp = (uint4*)(A1h + (size_t)n * 16);
        yp[0] = pk.u4[0];
        yp[1] = pk.u4[1];
    }
}

__device__ __forceinline__ void add8(float* a, uint4 v) {
    float2 f;
    f = __half22float2(*(const __half2*)&v.x); a[0] += f.x; a[1] += f.y;
    f = __half22float2(*(const __half2*)&v.y); a[2] += f.x; a[3] += f.y;
    f = __half22float2(*(const __half2*)&v.z); a[4] += f.x; a[5] += f.y;
    f = __half22float2(*(const __half2*)&v.w); a[6] += f.x; a[7] += f.y;
}

// 8-wide unrolled gather-accumulate over an edge range (8 outstanding L2 loads/lane)
__device__ __forceinline__ void gather_range(const uint4* __restrict__ H4,
                                             const int* __restrict__ csr,
                                             int e, int end, int q, float* acc) {
    for (; e + 7 < end; e += 8) {
        int s0 = csr[e],   s1 = csr[e+1], s2 = csr[e+2], s3 = csr[e+3];
        int s4 = csr[e+4], s5 = csr[e+5], s6 = csr[e+6], s7 = csr[e+7];
        uint4 g0 = H4[(size_t)s0 * 2 + q];
        uint4 g1 = H4[(size_t)s1 * 2 + q];
        uint4 g2 = H4[(size_t)s2 * 2 + q];
        uint4 g3 = H4[(size_t)s3 * 2 + q];
        uint4 g4 = H4[(size_t)s4 * 2 + q];
        uint4 g5 = H4[(size_t)s5 * 2 + q];
        uint4 g6 = H4[(size_t)s6 * 2 + q];
        uint4 g7 = H4[(size_t)s7 * 2 + q];
        add8(acc, g0); add8(acc, g1); add8(acc, g2); add8(acc, g3);
        add8(acc, g4); add8(acc, g5); add8(acc, g6); add8(acc, g7);
    }
    for (; e + 3 < end; e += 4) {
        int s0 = csr[e], s1 = csr[e+1], s2 = csr[e+2], s3 = csr[e+3];
        uint4 g0 = H4[(size_t)s0 * 2 + q];
        uint4 g1 = H4[(size_t)s1 * 2 + q];
        uint4 g2 = H4[(size_t)s2 * 2 + q];
        uint4 g3 = H4[(size_t)s3 * 2 + q];
        add8(acc, g0); add8(acc, g1); add8(acc, g2); add8(acc, g3);
    }
    for (; e < end; e++) add8(acc, H4[(size_t)csr[e] * 2 + q]);
}

// ---- K3 layer-1: gather (2 lanes/node, 8-way unroll); relu(dinv*sum+b1); @W2^T*dinv ----
__global__ void __launch_bounds__(256) agg1_kernel(
    const int* __restrict__ rowptr, const int* __restrict__ csr,
    const __half* __restrict__ A1h, const float* __restrict__ b1,
    const float* __restrict__ W2, __half* __restrict__ A2h, int N) {
    __shared__ float sW2[256];
    __shared__ float sb1[16];
    __shared__ float tile[128][17];
    int t = threadIdx.x;
    int team = t >> 1, q = t & 1;
    int node = blockIdx.x * 128 + team;
    sW2[t] = W2[t];
    if (t < 16) sb1[t] = b1[t];
    __syncthreads();
    const uint4* H4 = (const uint4*)A1h;
    float dd = 0.f;
    if (node < N) {
        int e = rowptr[node], end = rowptr[node + 1];
        dd = rsqrtf((float)(end - e) + 1.0f);
        float acc[8] = {0.f,0.f,0.f,0.f,0.f,0.f,0.f,0.f};
        add8(acc, H4[(size_t)node * 2 + q]);   // self (pre-scaled by dinv)
        gather_range(H4, csr, e, end, q, acc);
#pragma unroll
        for (int j = 0; j < 8; j++)
            tile[team][q * 8 + j] = fmaxf(acc[j] * dd + sb1[q * 8 + j], 0.f);
    }
    __syncthreads();
    if (node < N) {
        float o[8];
#pragma unroll
        for (int jj = 0; jj < 8; jj++) {
            int j = q * 8 + jj;
            float a = 0.f;
#pragma unroll
            for (int k = 0; k < 16; k++) a += tile[team][k] * sW2[j * 16 + k];
            o[jj] = a * dd;
        }
        uint4 ov;
        ((__half2*)&ov)[0] = __floats2half2_rn(o[0], o[1]);
        ((__half2*)&ov)[1] = __floats2half2_rn(o[2], o[3]);
        ((__half2*)&ov)[2] = __floats2half2_rn(o[4], o[5]);
        ((__half2*)&ov)[3] = __floats2half2_rn(o[6], o[7]);
        ((uint4*)A2h)[(size_t)node * 2 + q] = ov;
    }
}

// ---- K4 layer-2: gather (8-way unroll); dinv*sum; segmented mean-pool flush ----
__global__ void __launch_bounds__(256) agg2_kernel(
    const int* __restrict__ rowptr, const int* __restrict__ csr,
    const __half* __restrict__ A2h, const int* __restrict__ batch,
    float* __restrict__ pooled, float* __restrict__ cnt, int N) {
    __shared__ float tile[128][17];
    __shared__ int gb[128];
    int t = threadIdx.x;
    int team = t >> 1, q = t & 1;
    int base = blockIdx.x * 128;
    int node = base + team;
    if (t < 128) {
        int n = base + t;
        gb[t] = (n < N) ? batch[n] : -1;
    }
    const uint4* H4 = (const uint4*)A2h;
    if (node < N) {
        int e = rowptr[node], end = rowptr[node + 1];
        float dd = rsqrtf((float)(end - e) + 1.0f);
        float acc[8] = {0.f,0.f,0.f,0.f,0.f,0.f,0.f,0.f};
        add8(acc, H4[(size_t)node * 2 + q]);   // self
        gather_range(H4, csr, e, end, q, acc);
#pragma unroll
        for (int j = 0; j < 8; j++) tile[team][q * 8 + j] = acc[j] * dd;
    }
    __syncthreads();
    int nmax = N - base; if (nmax > 128) nmax = 128;
    if (t < 16 && nmax > 0) {
        int c = t;
        int g = gb[0];
        float a = 0.f, k = 0.f;
        for (int n = 0; n < nmax; n++) {
            int gi = gb[n];
            if (gi != g) {
                atomicAdd(&pooled[(size_t)g * 16 + c], a);
                if (c == 0) atomicAdd(&cnt[g], k);
                a = 0.f; k = 0.f; g = gi;
            }
            a += tile[n][c];
            k += 1.f;
        }
        atomicAdd(&pooled[(size_t)g * 16 + c], a);
        if (c == 0) atomicAdd(&cnt[g], k);
    }
}

// ---- K5 head: mean finish (+b2), logits = pooled @ Wl^T + bl, softmax ----
__global__ void head_kernel(const float* __restrict__ pooled, const float* __restrict__ cnt,
                            const float* __restrict__ b2, const float* __restrict__ Wl,
                            const float* __restrict__ bl, float* __restrict__ out) {
    int g = blockIdx.x * blockDim.x + threadIdx.x;
    if (g >= NG) return;
    float c = cnt[g];
    c = c > 1.0f ? c : 1.0f;
    float inv = 1.0f / c;
    float p[16];
#pragma unroll
    for (int j = 0; j < 16; j++) p[j] = pooled[(size_t)g * 16 + j] * inv + b2[j];
    float logits[5], m = -INFINITY;
#pragma unroll
    for (int r = 0; r < 5; r++) {
        float a = bl[r];
#pragma unroll
        for (int j = 0; j < 16; j++) a += p[j] * Wl[r * 16 + j];
        logits[r] = a;
        m = fmaxf(m, a);
    }
    float s = 0.f;
#pragma unroll
    for (int r = 0; r < 5; r++) { logits[r] = expf(logits[r] - m); s += logits[r]; }
    float is = 1.0f / s;
#pragma unroll
    for (int r = 0; r < 5; r++) out[(size_t)g * 5 + r] = logits[r] * is;
}

static inline size_t rnd16b(size_t bytes) { return (bytes + 15) & ~(size_t)15; }

extern "C" void kernel_launch(void* const* d_in, const int* in_sizes, int n_in,
                              void* d_out, int out_size, void* d_ws, size_t ws_size,
                              hipStream_t stream) {
    const float* x     = (const float*)d_in[0];
    const int*   edge  = (const int*)d_in[1];   // [2, E]: first E = src, next E = dst
    const int*   batch = (const int*)d_in[2];
    const float* W1    = (const float*)d_in[3];
    const float* b1    = (const float*)d_in[4];
    const float* W2    = (const float*)d_in[5];
    const float* b2    = (const float*)d_in[6];
    const float* Wl    = (const float*)d_in[7];
    const float* bl    = (const float*)d_in[8];

    const int N = in_sizes[0] / 32;
    const int E = in_sizes[1] / 2;
    const int* src = edge;
    const int* dst = edge + E;

    const int NPART = (N + NPN - 1) / NPN;   // 196 for N=100K
    const int CH = (E + K1BLK - 1) / K1BLK;

    // workspace layout; zeroed region (pooled|cnt|gcnt) first
    char* ws = (char*)d_ws;
    size_t off = 0;
    float*    pooled = (float*)(ws + off);    off += rnd16b((size_t)NG * 16 * 4);
    float*    cnt    = (float*)(ws + off);    off += rnd16b((size_t)NG * 4);
    int*      gcnt   = (int*)(ws + off);      off += rnd16b((size_t)MAXPART * 4);
    size_t zbytes = off;
    int*      rowptr = (int*)(ws + off);      off += rnd16b((size_t)(N + 1) * 4);
    int*      ibuf   = (int*)(ws + off);      off += rnd16b((size_t)NPART * CAP * 4);
    int*      csr    = (int*)(ws + off);      off += rnd16b((size_t)E * 4);
    __half*   A1h    = (__half*)(ws + off);   off += rnd16b((size_t)N * 16 * 2);
    __half*   A2h    = (__half*)(ws + off);   off += rnd16b((size_t)N * 16 * 2);

    int z4 = (int)(zbytes / 16);

    // CSR build: atomic-reserve scatter into CAP-strided regions, then packed CSR
    init_kernel<<<(z4 + 255) / 256, 256, 0, stream>>>((int4*)d_ws, z4);
    scatter_kernel<<<K1BLK, 256, 0, stream>>>(src, dst, gcnt, ibuf, E, CH, NPART);
    part_kernel<<<NPART, 256, 0, stream>>>(gcnt, ibuf, csr, rowptr, x, W1, A1h, N, E, NPART);

    // two fused conv layers + head
    int gAgg = (N + 127) / 128;
    agg1_kernel<<<gAgg, 256, 0, stream>>>(rowptr, csr, A1h, b1, W2, A2h, N);
    agg2_kernel<<<gAgg, 256, 0, stream>>>(rowptr, csr, A2h, batch, pooled, cnt, N);
    head_kernel<<<(NG + 255) / 256, 256, 0, stream>>>(pooled, cnt, b2, Wl, bl, (float*)d_out);
}

// Round 17
// 103.027 us; speedup vs baseline: 1.0627x; 1.0627x over previous
//
#include <hip/hip_runtime.h>
#include <hip/hip_fp16.h>
#include <math.h>

#define NG 1000
#define NPN 512        // nodes per partition
#define PSH 9          // log2(NPN)
#define MAXPART 256    // >= ceil(N/NPN); N=100K -> 196
#define K1BLK 256      // blocks for edge-chunk kernels

// ---- K1: per-block partition histogram (transposed bhist[p][b]) + zero pooled/cnt ----
__global__ void __launch_bounds__(256) hist_kernel(const int* __restrict__ dst,
                                                   int* __restrict__ bhist,
                                                   int4* __restrict__ zero4, int z4,
                                                   int E, int CH) {
    __shared__ int h[MAXPART];
    int b = blockIdx.x, t = threadIdx.x;
    h[t] = 0;
    int gid = b * 256 + t;
    if (gid < z4) zero4[gid] = make_int4(0, 0, 0, 0);
    __syncthreads();
    int beg = b * CH, end = min(E, beg + CH);
    for (int e = beg + t; e < end; e += 256) atomicAdd(&h[dst[e] >> PSH], 1);
    __syncthreads();
    bhist[t * K1BLK + b] = h[t];   // transposed: partition-major
}

// ---- K2a: per-partition exclusive prefix over blocks (1 wave per partition) ----
__global__ void __launch_bounds__(256) scanA_kernel(const int* __restrict__ bhist,
                                                    int* __restrict__ gbase,
                                                    int* __restrict__ pcnt, int NPART) {
    int wid = blockIdx.x * 4 + (threadIdx.x >> 6);
    int lane = threadIdx.x & 63;
    if (wid >= NPART) return;
    int base = wid * K1BLK + lane * 4;
    int v0 = bhist[base + 0], v1 = bhist[base + 1];
    int v2 = bhist[base + 2], v3 = bhist[base + 3];
    int s = v0 + v1 + v2 + v3;
    int incl = s;
    for (int off = 1; off < 64; off <<= 1) {
        int u = __shfl_up(incl, off);
        if (lane >= off) incl += u;
    }
    int run = incl - s;
    gbase[base + 0] = run;            run += v0;
    gbase[base + 1] = run;            run += v1;
    gbase[base + 2] = run;            run += v2;
    gbase[base + 3] = run;
    if (lane == 63) pcnt[wid] = incl;
}

// ---- K2b: scan partition totals -> poff (one wave) ----
__global__ void __launch_bounds__(64) scanB_kernel(const int* __restrict__ pcnt,
                                                   int* __restrict__ poff,
                                                   int* __restrict__ rowptr,
                                                   int NPART, int N, int E) {
    int lane = threadIdx.x;
    int v[4];
    int s = 0;
#pragma unroll
    for (int k = 0; k < 4; k++) {
        int idx = lane * 4 + k;
        v[k] = (idx < NPART) ? pcnt[idx] : 0;
        s += v[k];
    }
    int incl = s;
    for (int off = 1; off < 64; off <<= 1) {
        int u = __shfl_up(incl, off);
        if (lane >= off) incl += u;
    }
    int run = incl - s;
#pragma unroll
    for (int k = 0; k < 4; k++) {
        int idx = lane * 4 + k;
        if (idx < NPART) poff[idx] = run;
        run += v[k];
    }
    int grand = __shfl(incl, 63);
    if (lane == 0) { poff[NPART] = grand; rowptr[N] = E; }
}

// ---- K3: scatter edges into partition-grouped ibuf; pre-reserved cursors, LDS atomics ----
__global__ void __launch_bounds__(256) scatter_kernel(const int* __restrict__ src,
                                                      const int* __restrict__ dst,
                                                      const int* __restrict__ poff,
                                                      const int* __restrict__ gbase,
                                                      int* __restrict__ ibuf,
                                                      int E, int CH, int NPART) {
    __shared__ int cur[MAXPART];
    int b = blockIdx.x, t = threadIdx.x;
    if (t < NPART) cur[t] = poff[t] + gbase[t * K1BLK + b];   // transposed gbase
    __syncthreads();
    int beg = b * CH, end = min(E, beg + CH);
    for (int e = beg + t; e < end; e += 256) {
        int s = src[e], d = dst[e];
        int p = d >> PSH;
        int pos = atomicAdd(&cur[p], 1);
        ibuf[pos] = ((d & (NPN - 1)) << 17) | s;   // N < 2^17
    }
}

// ---- K4: per-partition node CSR + rowptr + dinv + fused A1h = (x@W1^T)*dinv ----
__global__ void __launch_bounds__(256) part_kernel(const int* __restrict__ poff,
                                                   const int* __restrict__ ibuf,
                                                   int* __restrict__ csr,
                                                   int* __restrict__ rowptr,
                                                   float* __restrict__ dinv,
                                                   const float* __restrict__ X,
                                                   const float* __restrict__ W1,
                                                   __half* __restrict__ A1h, int N) {
    __shared__ int h[NPN];
    __shared__ int ex[NPN];
    __shared__ int cur[NPN];
    __shared__ int sm[256];
    __shared__ float sW1[512];
    int p = blockIdx.x, t = threadIdx.x;
    int base = p * NPN;
    for (int k = t; k < NPN; k += 256) h[k] = 0;
    sW1[t] = W1[t];
    sW1[t + 256] = W1[t + 256];
    __syncthreads();
    int ebeg = poff[p], eend = poff[p + 1];
    for (int e = ebeg + t; e < eend; e += 256) atomicAdd(&h[ibuf[e] >> 17], 1);
    __syncthreads();
    int a0 = h[2 * t], a1 = h[2 * t + 1];
    int s = a0 + a1;
    sm[t] = s;
    __syncthreads();
    for (int o = 1; o < 256; o <<= 1) {
        int u = (t >= o) ? sm[t - o] : 0;
        __syncthreads();
        sm[t] += u;
        __syncthreads();
    }
    int exc = sm[t] - s;
    ex[2 * t] = exc;          cur[2 * t] = exc;
    ex[2 * t + 1] = exc + a0; cur[2 * t + 1] = exc + a0;
    __syncthreads();
    for (int k = t; k < NPN; k += 256) {
        int n = base + k;
        if (n < N) {
            rowptr[n] = ebeg + ex[k];
            dinv[n] = rsqrtf((float)h[k] + 1.0f);   // +1 self-loop
        }
    }
    for (int e = ebeg + t; e < eend; e += 256) {
        int w = ibuf[e];
        int ln = w >> 17;
        int pos = ebeg + atomicAdd(&cur[ln], 1);
        csr[pos] = w & 0x1FFFF;
    }
    // fused xform: A1h[n] = (x[n] @ W1^T) * dinv[n]
    for (int k = t; k < NPN; k += 256) {
        int n = base + k;
        if (n >= N) continue;
        float dd = rsqrtf((float)h[k] + 1.0f);
        float xv[32];
        const float4* xp = (const float4*)(X + (size_t)n * 32);
#pragma unroll
        for (int qq = 0; qq < 8; qq++) {
            float4 v = xp[qq];
            xv[4*qq+0] = v.x; xv[4*qq+1] = v.y; xv[4*qq+2] = v.z; xv[4*qq+3] = v.w;
        }
        union { __half2 h2[8]; uint4 u4[2]; } pk;
#pragma unroll
        for (int j2 = 0; j2 < 8; j2++) {
            float o[2];
#pragma unroll
            for (int jj = 0; jj < 2; jj++) {
                int j = j2 * 2 + jj;
                float a = 0.f;
#pragma unroll
                for (int kk = 0; kk < 32; kk++) a += xv[kk] * sW1[j * 32 + kk];
                o[jj] = a * dd;
            }
            pk.h2[j2] = __floats2half2_rn(o[0], o[1]);
        }
        uint4* yp = (uint4*)(A1h + (size_t)n * 16);
        yp[0] = pk.u4[0];
        yp[1] = pk.u4[1];
    }
}

__device__ __forceinline__ void add8(float* a, uint4 v) {
    float2 f;
    f = __half22float2(*(const __half2*)&v.x); a[0] += f.x; a[1] += f.y;
    f = __half22float2(*(const __half2*)&v.y); a[2] += f.x; a[3] += f.y;
    f = __half22float2(*(const __half2*)&v.z); a[4] += f.x; a[5] += f.y;
    f = __half22float2(*(const __half2*)&v.w); a[6] += f.x; a[7] += f.y;
}

// ---- K5 layer-1: gather (2 lanes/node, 4-way unroll); relu(dinv*sum+b1); @W2^T*dinv ----
__global__ void __launch_bounds__(256) agg1_kernel(
    const int* __restrict__ rowptr, const int* __restrict__ csr,
    const float* __restrict__ dinv, const __half* __restrict__ A1h,
    const float* __restrict__ b1, const float* __restrict__ W2,
    __half* __restrict__ A2h, int N) {
    __shared__ float sW2[256];
    __shared__ float sb1[16];
    __shared__ float tile[128][17];
    int t = threadIdx.x;
    int team = t >> 1, q = t & 1;
    int node = blockIdx.x * 128 + team;
    sW2[t] = W2[t];
    if (t < 16) sb1[t] = b1[t];
    __syncthreads();
    const uint4* H4 = (const uint4*)A1h;
    float dd = 0.f;
    if (node < N) {
        dd = dinv[node];
        float acc[8] = {0.f,0.f,0.f,0.f,0.f,0.f,0.f,0.f};
        add8(acc, H4[(size_t)node * 2 + q]);   // self (pre-scaled by dinv)
        int e = rowptr[node], end = rowptr[node + 1];
        for (; e + 3 < end; e += 4) {
            int s0 = csr[e], s1 = csr[e+1], s2 = csr[e+2], s3 = csr[e+3];
            uint4 g0 = H4[(size_t)s0 * 2 + q];
            uint4 g1 = H4[(size_t)s1 * 2 + q];
            uint4 g2 = H4[(size_t)s2 * 2 + q];
            uint4 g3 = H4[(size_t)s3 * 2 + q];
            add8(acc, g0); add8(acc, g1); add8(acc, g2); add8(acc, g3);
        }
        for (; e < end; e++) add8(acc, H4[(size_t)csr[e] * 2 + q]);
#pragma unroll
        for (int j = 0; j < 8; j++)
            tile[team][q * 8 + j] = fmaxf(acc[j] * dd + sb1[q * 8 + j], 0.f);
    }
    __syncthreads();
    if (node < N) {
        float o[8];
#pragma unroll
        for (int jj = 0; jj < 8; jj++) {
            int j = q * 8 + jj;
            float a = 0.f;
#pragma unroll
            for (int k = 0; k < 16; k++) a += tile[team][k] * sW2[j * 16 + k];
            o[jj] = a * dd;
        }
        uint4 ov;
        ((__half2*)&ov)[0] = __floats2half2_rn(o[0], o[1]);
        ((__half2*)&ov)[1] = __floats2half2_rn(o[2], o[3]);
        ((__half2*)&ov)[2] = __floats2half2_rn(o[4], o[5]);
        ((__half2*)&ov)[3] = __floats2half2_rn(o[6], o[7]);
        ((uint4*)A2h)[(size_t)node * 2 + q] = ov;
    }
}

// ---- K6 layer-2: gather; dinv*sum; segmented mean-pool flush ----
__global__ void __launch_bounds__(256) agg2_kernel(
    const int* __restrict__ rowptr, const int* __restrict__ csr,
    const float* __restrict__ dinv, const __half* __restrict__ A2h,
    const int* __restrict__ batch, float* __restrict__ pooled,
    float* __restrict__ cnt, int N) {
    __shared__ float tile[128][17];
    __shared__ int gb[128];
    int t = threadIdx.x;
    int team = t >> 1, q = t & 1;
    int base = blockIdx.x * 128;
    int node = base + team;
    if (t < 128) {
        int n = base + t;
        gb[t] = (n < N) ? batch[n] : -1;
    }
    const uint4* H4 = (const uint4*)A2h;
    if (node < N) {
        float dd = dinv[node];
        float acc[8] = {0.f,0.f,0.f,0.f,0.f,0.f,0.f,0.f};
        add8(acc, H4[(size_t)node * 2 + q]);   // self
        int e = rowptr[node], end = rowptr[node + 1];
        for (; e + 3 < end; e += 4) {
            int s0 = csr[e], s1 = csr[e+1], s2 = csr[e+2], s3 = csr[e+3];
            uint4 g0 = H4[(size_t)s0 * 2 + q];
            uint4 g1 = H4[(size_t)s1 * 2 + q];
            uint4 g2 = H4[(size_t)s2 * 2 + q];
            uint4 g3 = H4[(size_t)s3 * 2 + q];
            add8(acc, g0); add8(acc, g1); add8(acc, g2); add8(acc, g3);
        }
        for (; e < end; e++) add8(acc, H4[(size_t)csr[e] * 2 + q]);
#pragma unroll
        for (int j = 0; j < 8; j++) tile[team][q * 8 + j] = acc[j] * dd;
    }
    __syncthreads();
    int nmax = N - base; if (nmax > 128) nmax = 128;
    if (t < 16 && nmax > 0) {
        int c = t;
        int g = gb[0];
        float a = 0.f, k = 0.f;
        for (int n = 0; n < nmax; n++) {
            int gi = gb[n];
            if (gi != g) {
                atomicAdd(&pooled[(size_t)g * 16 + c], a);
                if (c == 0) atomicAdd(&cnt[g], k);
                a = 0.f; k = 0.f; g = gi;
            }
            a += tile[n][c];
            k += 1.f;
        }
        atomicAdd(&pooled[(size_t)g * 16 + c], a);
        if (c == 0) atomicAdd(&cnt[g], k);
    }
}

// ---- K7 head: mean finish (+b2), logits = pooled @ Wl^T + bl, softmax ----
__global__ void head_kernel(const float* __restrict__ pooled, const float* __restrict__ cnt,
                            const float* __restrict__ b2, const float* __restrict__ Wl,
                            const float* __restrict__ bl, float* __restrict__ out) {
    int g = blockIdx.x * blockDim.x + threadIdx.x;
    if (g >= NG) return;
    float c = cnt[g];
    c = c > 1.0f ? c : 1.0f;
    float inv = 1.0f / c;
    float p[16];
#pragma unroll
    for (int j = 0; j < 16; j++) p[j] = pooled[(size_t)g * 16 + j] * inv + b2[j];
    float logits[5], m = -INFINITY;
#pragma unroll
    for (int r = 0; r < 5; r++) {
        float a = bl[r];
#pragma unroll
        for (int j = 0; j < 16; j++) a += p[j] * Wl[r * 16 + j];
        logits[r] = a;
        m = fmaxf(m, a);
    }
    float s = 0.f;
#pragma unroll
    for (int r = 0; r < 5; r++) { logits[r] = expf(logits[r] - m); s += logits[r]; }
    float is = 1.0f / s;
#pragma unroll
    for (int r = 0; r < 5; r++) out[(size_t)g * 5 + r] = logits[r] * is;
}

static inline size_t rnd16b(size_t bytes) { return (bytes + 15) & ~(size_t)15; }

extern "C" void kernel_launch(void* const* d_in, const int* in_sizes, int n_in,
                              void* d_out, int out_size, void* d_ws, size_t ws_size,
                              hipStream_t stream) {
    const float* x     = (const float*)d_in[0];
    const int*   edge  = (const int*)d_in[1];   // [2, E]: first E = src, next E = dst
    const int*   batch = (const int*)d_in[2];
    const float* W1    = (const float*)d_in[3];
    const float* b1    = (const float*)d_in[4];
    const float* W2    = (const float*)d_in[5];
    const float* b2    = (const float*)d_in[6];
    const float* Wl    = (const float*)d_in[7];
    const float* bl    = (const float*)d_in[8];

    const int N = in_sizes[0] / 32;
    const int E = in_sizes[1] / 2;
    const int* src = edge;
    const int* dst = edge + E;

    const int NPART = (N + NPN - 1) / NPN;   // 196 for N=100K
    const int CH = (E + K1BLK - 1) / K1BLK;

    // workspace layout; zeroed region (pooled|cnt) first
    char* ws = (char*)d_ws;
    size_t off = 0;
    float*    pooled = (float*)(ws + off);    off += rnd16b((size_t)NG * 16 * 4);
    float*    cnt    = (float*)(ws + off);    off += rnd16b((size_t)NG * 4);
    size_t zbytes = off;
    int*      poff   = (int*)(ws + off);      off += rnd16b((size_t)(MAXPART + 1) * 4);
    int*      pcnt   = (int*)(ws + off);      off += rnd16b((size_t)MAXPART * 4);
    int*      rowptr = (int*)(ws + off);      off += rnd16b((size_t)(N + 1) * 4);
    float*    dinv   = (float*)(ws + off);    off += rnd16b((size_t)N * 4);
    int*      bhist  = (int*)(ws + off);      off += rnd16b((size_t)K1BLK * MAXPART * 4);
    int*      gbase  = (int*)(ws + off);      off += rnd16b((size_t)K1BLK * MAXPART * 4);
    int*      ibuf   = (int*)(ws + off);      off += rnd16b((size_t)E * 4);
    int*      csr    = (int*)(ws + off);      off += rnd16b((size_t)E * 4);
    __half*   A1h    = (__half*)(ws + off);   off += rnd16b((size_t)N * 16 * 2);
    __half*   A2h    = (__half*)(ws + off);   off += rnd16b((size_t)N * 16 * 2);

    int z4 = (int)(zbytes / 16);

    // CSR build: atomic-free two-pass radix by dst, parallel scans
    hist_kernel<<<K1BLK, 256, 0, stream>>>(dst, bhist, (int4*)d_ws, z4, E, CH);
    scanA_kernel<<<(NPART + 3) / 4, 256, 0, stream>>>(bhist, gbase, pcnt, NPART);
    scanB_kernel<<<1, 64, 0, stream>>>(pcnt, poff, rowptr, NPART, N, E);
    scatter_kernel<<<K1BLK, 256, 0, stream>>>(src, dst, poff, gbase, ibuf, E, CH, NPART);
    part_kernel<<<NPART, 256, 0, stream>>>(poff, ibuf, csr, rowptr, dinv, x, W1, A1h, N);

    // two fused conv layers + head
    int gAgg = (N + 127) / 128;
    agg1_kernel<<<gAgg, 256, 0, stream>>>(rowptr, csr, dinv, A1h, b1, W2, A2h, N);
    agg2_kernel<<<gAgg, 256, 0, stream>>>(rowptr, csr, dinv, A2h, batch, pooled, cnt, N);
    head_kernel<<<(NG + 255) / 256, 256, 0, stream>>>(pooled, cnt, b2, Wl, bl, (float*)d_out);
}